// Round 9
// baseline (185.070 us; speedup 1.0000x reference)
//
#include <hip/hip_runtime.h>
#include <math.h>

#define L_ 64
#define LCHUNK 16            // l's per block in kernel B (grid.y = 4)
#define HPf 1.57079632679489661923f
#define TIE_THR 4e-3f        // f16-split dot err ~1.7e-4 < fp32's 4e-4 bound -> same proof

typedef _Float16 half4 __attribute__((ext_vector_type(4)));
typedef float    f32x4 __attribute__((ext_vector_type(4)));

// split fp32 vec4 -> f16 hi + f16 lo (x = hi + lo + O(2^-22 x))
#define CVT4(H, L, V) {                                                       \
    _Float16 h0=(_Float16)(V).x, h1=(_Float16)(V).y,                          \
             h2=(_Float16)(V).z, h3=(_Float16)(V).w;                          \
    (H) = (half4){h0, h1, h2, h3};                                            \
    (L) = (half4){(_Float16)((V).x-(float)h0), (_Float16)((V).y-(float)h1),   \
                  (_Float16)((V).z-(float)h2), (_Float16)((V).w-(float)h3)};  \
}

// ---------------- Kernel P: per-l scalar table (64 threads) ----------------
// table row l (16 floats): [0]n0 [1]n1 [2]n2 [3]C01 [4]C02 [5]C12
//                          [6]angS_sq [7]lenS_sq [8]esq [9]csq [10]ssqf
__global__ __launch_bounds__(64)
void setconvP(const float* __restrict__ x_support,
              const float* __restrict__ edge_sup,
              const float* __restrict__ x_center,
              const float* __restrict__ p_support,
              float* __restrict__ table)
{
    const int l = threadIdx.x;
    if (l >= L_) return;

    const float* xs = x_support + (size_t)l * 96;
    double ssq = 0.0;
    for (int i = 0; i < 96; ++i) { double v = (double)xs[i]; ssq += v * v; }

    const float* es = edge_sup + (size_t)l * 24;
    float esq = 0.f;
    for (int i = 0; i < 24; ++i) esq = fmaf(es[i], es[i], esq);

    const float* xc = x_center + (size_t)l * 32;
    float csq = 0.f;
    for (int i = 0; i < 32; ++i) csq = fmaf(xc[i], xc[i], csq);

    float p0[3], p1[3], p2[3];
    for (int d = 0; d < 3; ++d) {
        p0[d] = p_support[(l * 3 + 0) * 3 + d];
        p1[d] = p_support[(l * 3 + 1) * 3 + d];
        p2[d] = p_support[(l * 3 + 2) * 3 + d];
    }
    float n0 = sqrtf(p0[0]*p0[0] + p0[1]*p0[1] + p0[2]*p0[2]);
    float n1 = sqrtf(p1[0]*p1[0] + p1[1]*p1[1] + p1[2]*p1[2]);
    float n2 = sqrtf(p2[0]*p2[0] + p2[1]*p2[1] + p2[2]*p2[2]);
    float d01 = p0[0]*p1[0] + p0[1]*p1[1] + p0[2]*p1[2];
    float d02 = p0[0]*p2[0] + p0[1]*p2[1] + p0[2]*p2[2];
    float d12 = p1[0]*p2[0] + p1[1]*p2[1] + p1[2]*p2[2];
    float C01 = d01 / fmaxf(n0 * n1, 1e-8f);
    float C02 = d02 / fmaxf(n0 * n2, 1e-8f);
    float C12 = d12 / fmaxf(n1 * n2, 1e-8f);

    float* t = table + l * 16;
    t[0] = n0;  t[1] = n1;  t[2] = n2;
    t[3] = C01; t[4] = C02; t[5] = C12;
    t[6] = C01*C01 + C02*C02 + C12*C12;
    t[7] = n0*n0 + n1*n1 + n2*n2;
    t[8] = esq;
    t[9] = csq;
    t[10] = (float)ssq;
}

// ---------------- Kernel A (MFMA): support argmax + tie worklist ------------
// GEMM view: C[nm][c] = dot(xn[n,m,:], xs[c,:]), M = n*4+m (m=3 zero-pad),
// N' = 192 support rows (12 col-tiles of 16), K = 32 (2 halves of 16).
// v_mfma_f32_16x16x16_f16 with fp32 = f16hi + f16lo 3-pass split.
// Per wave: B frags (all 192 cols) resident in regs; 8 chunks x 4 n's.
__global__ __launch_bounds__(256)
void setconvA_mfma(const float* __restrict__ x_neighbor,
                   const float* __restrict__ x_support,
                   const float* __restrict__ table,
                   float* __restrict__ out,
                   unsigned char* __restrict__ bestp,
                   int* __restrict__ wl_cnt,
                   int* __restrict__ wl,
                   int wl_cap,
                   int N)
{
    // per-wave C scratch: 192 cols x 16 rows, col stride 20 (bank spread)
    __shared__ float clds[4][192 * 20];

    const int tid  = threadIdx.x;
    const int w    = tid >> 6;          // wave in block
    const int lane = tid & 63;
    const int col  = lane & 15;         // A-row / B-col index
    const int kg   = lane >> 4;         // k-group 0..3 (k = 16h + 4kg + e)
    const int n_off = col >> 2;         // A rows: n_local*4 + m
    const int m     = col & 3;          // m==3 -> zero pad row

    const int n_start = (blockIdx.x * 4 + w) * 32;   // 8 chunks x 4 n

    // ---- B fragments: 12 tiles x 2 k-halves, hi+lo (persistent, ~96 VGPR) ----
    half4 bh[12][2], bl[12][2];
    #pragma unroll
    for (int t = 0; t < 12; ++t) {
        const float* bp = x_support + (size_t)(16 * t + col) * 32 + kg * 4;
        float4 v0 = *(const float4*)bp;
        float4 v1 = *(const float4*)(bp + 16);
        CVT4(bh[t][0], bl[t][0], v0);
        CVT4(bh[t][1], bl[t][1], v1);
    }

    const float4 z4 = make_float4(0.f, 0.f, 0.f, 0.f);

    // prefetch chunk 0's A rows
    float4 pv0, pv1;
    {
        int n_i = n_start + n_off;
        bool ok = (m < 3) && (n_i < N);
        const float* ap = x_neighbor + (size_t)n_i * 96 + m * 32 + kg * 4;
        pv0 = ok ? *(const float4*)ap        : z4;
        pv1 = ok ? *(const float4*)(ap + 16) : z4;
    }

    for (int c8 = 0; c8 < 8; ++c8) {
        const int n_base = n_start + c8 * 4;
        float4 va0 = pv0, va1 = pv1;
        if (c8 < 7) {
            int n_i = n_base + 4 + n_off;
            bool ok = (m < 3) && (n_i < N);
            const float* ap = x_neighbor + (size_t)n_i * 96 + m * 32 + kg * 4;
            pv0 = ok ? *(const float4*)ap        : z4;
            pv1 = ok ? *(const float4*)(ap + 16) : z4;
        }

        // nei_sq: per-lane row partial -> reduce over k-groups, then over m
        float rp = va0.x*va0.x + va0.y*va0.y + va0.z*va0.z + va0.w*va0.w
                 + va1.x*va1.x + va1.y*va1.y + va1.z*va1.z + va1.w*va1.w;
        rp += __shfl_xor(rp, 16);
        rp += __shfl_xor(rp, 32);            // rowsq[row], row = lane&15
        float tq = rp + __shfl_xor(rp, 1);
        float nsq4 = tq + __shfl_xor(tq, 2); // nei_sq of this lane's nibble-n

        // A fragments (hi/lo, 2 k-halves)
        half4 ah0, al0, ah1, al1;
        CVT4(ah0, al0, va0);
        CVT4(ah1, al1, va1);

        // ---- 72 MFMAs: 12 tiles x 2 k-halves x 3 precision passes ----
        f32x4 acc[12] = {};
        #pragma unroll
        for (int t = 0; t < 12; ++t) {
            acc[t] = __builtin_amdgcn_mfma_f32_16x16x16f16(ah0, bh[t][0], acc[t], 0, 0, 0);
            acc[t] = __builtin_amdgcn_mfma_f32_16x16x16f16(al0, bh[t][0], acc[t], 0, 0, 0);
            acc[t] = __builtin_amdgcn_mfma_f32_16x16x16f16(ah0, bl[t][0], acc[t], 0, 0, 0);
            acc[t] = __builtin_amdgcn_mfma_f32_16x16x16f16(ah1, bh[t][1], acc[t], 0, 0, 0);
            acc[t] = __builtin_amdgcn_mfma_f32_16x16x16f16(al1, bh[t][1], acc[t], 0, 0, 0);
            acc[t] = __builtin_amdgcn_mfma_f32_16x16x16f16(ah1, bl[t][1], acc[t], 0, 0, 0);
        }

        // ---- C -> LDS: lane holds rows 4kg..4kg+3 of col 16t+col ----
        #pragma unroll
        for (int t = 0; t < 12; ++t)
            *(f32x4*)&clds[w][(16 * t + col) * 20 + kg * 4] = acc[t];

        __syncthreads();

        // ---- epilogue: lane <-> (n_local = lane>>4, l = (lane&15)+16*it) ----
        const int nloc = lane >> 4;
        const int n_e  = n_base + nloc;
        const float nei_e = __shfl(nsq4, nloc * 4);

        #pragma unroll
        for (int it = 0; it < 4; ++it) {
            const int l = (lane & 15) + 16 * it;
            f32x4 q0 = *(const f32x4*)&clds[w][(3*l + 0) * 20 + nloc * 4];
            f32x4 q1 = *(const f32x4*)&clds[w][(3*l + 1) * 20 + nloc * 4];
            f32x4 q2 = *(const f32x4*)&clds[w][(3*l + 2) * 20 + nloc * 4];
            // cr[m][k] = q_k[m]; perm sum = q_a[0] + q_b[1] + q_c[2]
            float c0 = q0[0] + q1[1] + q2[2];   // (0,1,2) -> 6
            float c1 = q0[0] + q2[1] + q1[2];   // (0,2,1) -> 9
            float c2 = q1[0] + q0[1] + q2[2];   // (1,0,2) -> 18
            float c3 = q1[0] + q2[1] + q0[2];   // (1,2,0) -> 24
            float c4 = q2[0] + q0[1] + q1[2];   // (2,0,1) -> 33
            float c5 = q2[0] + q1[1] + q0[2];   // (2,1,0) -> 36

            float b1 = c0, b2 = -3.4e38f; int bpk = 6;
            if (c1 > b1) { b2 = b1; b1 = c1; bpk = 9;  } else if (c1 > b2) b2 = c1;
            if (c2 > b1) { b2 = b1; b1 = c2; bpk = 18; } else if (c2 > b2) b2 = c2;
            if (c3 > b1) { b2 = b1; b1 = c3; bpk = 24; } else if (c3 > b2) b2 = c3;
            if (c4 > b1) { b2 = b1; b1 = c4; bpk = 33; } else if (c4 > b2) b2 = c4;
            if (c5 > b1) { b2 = b1; b1 = c5; bpk = 36; } else if (c5 > b2) b2 = c5;

            if (n_e < N) {
                float ssqf = table[l * 16 + 10];
                float dist = nei_e + ssqf - 2.0f * b1;
                float t3 = atanf(1.0f / dist) - HPf;
                size_t idx = (size_t)l * N + n_e;
                out[idx]   = t3 * t3;
                bestp[idx] = (unsigned char)bpk;
                if (b1 - b2 <= TIE_THR) {
                    int slot = atomicAdd(wl_cnt, 1);
                    if (slot < wl_cap) wl[slot] = (int)idx;
                }
            }
        }
        __syncthreads();   // protect clds reuse across chunks
    }
}

// ---------------- Kernel A2: fp64 tie refinement (worklist) ----------------
__global__ __launch_bounds__(256)
void setconvA2(const float* __restrict__ x_neighbor,
               const float* __restrict__ x_support,
               float* __restrict__ out,
               unsigned char* __restrict__ bestp,
               const int* __restrict__ wl_cnt,
               const int* __restrict__ wl,
               int wl_cap,
               int N)
{
    int cnt = *wl_cnt; if (cnt > wl_cap) cnt = wl_cap;
    const int stride = gridDim.x * blockDim.x;
    for (int i = blockIdx.x * blockDim.x + threadIdx.x; i < cnt; i += stride) {
        const int idx = wl[i];
        const int l = idx / N;
        const int n = idx - l * N;
        const float* xn = x_neighbor + (size_t)n * 96;
        const float* xs = x_support  + (size_t)l * 96;

        double dr[3][3] = {{0,0,0},{0,0,0},{0,0,0}};
        double nei = 0.0, ssq = 0.0;
        for (int f = 0; f < 32; ++f) {
            double a0 = (double)xn[f], a1 = (double)xn[32 + f], a2 = (double)xn[64 + f];
            double b0 = (double)xs[f], b1 = (double)xs[32 + f], b2 = (double)xs[64 + f];
            dr[0][0] += a0 * b0; dr[0][1] += a0 * b1; dr[0][2] += a0 * b2;
            dr[1][0] += a1 * b0; dr[1][1] += a1 * b1; dr[1][2] += a1 * b2;
            dr[2][0] += a2 * b0; dr[2][1] += a2 * b1; dr[2][2] += a2 * b2;
            nei += a0 * a0 + a1 * a1 + a2 * a2;
            ssq += b0 * b0 + b1 * b1 + b2 * b2;
        }
        double d0 = dr[0][0] + dr[1][1] + dr[2][2];
        double d1 = dr[0][0] + dr[1][2] + dr[2][1];
        double d2 = dr[0][1] + dr[1][0] + dr[2][2];
        double d3 = dr[0][1] + dr[1][2] + dr[2][0];
        double d4 = dr[0][2] + dr[1][0] + dr[2][1];
        double d5 = dr[0][2] + dr[1][1] + dr[2][0];
        double db = d0; int bpk = 6;
        if (d1 > db) { db = d1; bpk = 9;  }
        if (d2 > db) { db = d2; bpk = 18; }
        if (d3 > db) { db = d3; bpk = 24; }
        if (d4 > db) { db = d4; bpk = 33; }
        if (d5 > db) { db = d5; bpk = 36; }

        float dist = (float)(nei + (double)((float)ssq) - 2.0 * db);
        float t3 = atanf(1.0f / dist) - HPf;
        out[idx]   = t3 * t3;
        bestp[idx] = (unsigned char)bpk;
    }
}

// ---------------- Kernel B: value-only scores (fp32, SGPR operands) --------
__global__ __launch_bounds__(128)
void setconvB(const float* __restrict__ x_focal,
              const float* __restrict__ p_focal,
              const float* __restrict__ p_neighbor,
              const float* __restrict__ edge_nei,
              const float* __restrict__ x_center,
              const float* __restrict__ edge_sup,
              const float* __restrict__ table,
              const unsigned char* __restrict__ bestp,
              float* __restrict__ out,
              int N)
{
    const int tid = threadIdx.x;
    const int l0  = blockIdx.y * LCHUNK;
    const int n = blockIdx.x * 128 + tid;
    if (n >= N) return;

    float ed[24], xf[32];
    {
        const float4* q = (const float4*)(edge_nei + (size_t)n * 24);
        #pragma unroll
        for (int i = 0; i < 6; ++i) {
            float4 v = q[i];
            ed[4*i+0] = v.x; ed[4*i+1] = v.y; ed[4*i+2] = v.z; ed[4*i+3] = v.w;
        }
        const float4* r = (const float4*)(x_focal + (size_t)n * 32);
        #pragma unroll
        for (int i = 0; i < 8; ++i) {
            float4 v = r[i];
            xf[4*i+0] = v.x; xf[4*i+1] = v.y; xf[4*i+2] = v.z; xf[4*i+3] = v.w;
        }
    }

    float pr[3][3];
    {
        float pf0 = p_focal[(size_t)n*3 + 0];
        float pf1 = p_focal[(size_t)n*3 + 1];
        float pf2 = p_focal[(size_t)n*3 + 2];
        #pragma unroll
        for (int m = 0; m < 3; ++m) {
            pr[m][0] = p_neighbor[(size_t)n*9 + m*3 + 0] - pf0;
            pr[m][1] = p_neighbor[(size_t)n*9 + m*3 + 1] - pf1;
            pr[m][2] = p_neighbor[(size_t)n*9 + m*3 + 2] - pf2;
        }
    }
    float lenN0 = sqrtf(pr[0][0]*pr[0][0] + pr[0][1]*pr[0][1] + pr[0][2]*pr[0][2]);
    float lenN1 = sqrtf(pr[1][0]*pr[1][0] + pr[1][1]*pr[1][1] + pr[1][2]*pr[1][2]);
    float lenN2 = sqrtf(pr[2][0]*pr[2][0] + pr[2][1]*pr[2][1] + pr[2][2]*pr[2][2]);
    float angN0 = (pr[2][0]*pr[0][0] + pr[2][1]*pr[0][1] + pr[2][2]*pr[0][2]) / fmaxf(lenN2*lenN0, 1e-8f);
    float angN1 = (pr[0][0]*pr[1][0] + pr[0][1]*pr[1][1] + pr[0][2]*pr[1][2]) / fmaxf(lenN0*lenN1, 1e-8f);
    float angN2 = (pr[1][0]*pr[2][0] + pr[1][1]*pr[2][1] + pr[1][2]*pr[2][2]) / fmaxf(lenN1*lenN2, 1e-8f);
    float angN_sq = angN0*angN0 + angN1*angN1 + angN2*angN2;
    float lenN_sq = lenN0*lenN0 + lenN1*lenN1 + lenN2*lenN2;

    float edsq = 0.f, xfsq = 0.f;
    #pragma unroll
    for (int i = 0; i < 24; ++i) edsq = fmaf(ed[i], ed[i], edsq);
    #pragma unroll
    for (int i = 0; i < 32; ++i) xfsq = fmaf(xf[i], xf[i], xfsq);

    for (int ll = 0; ll < LCHUNK; ++ll) {
        const int l = l0 + ll;
        const float* es = edge_sup + (size_t)l * 24;   // uniform -> s_load
        const float* xc = x_center + (size_t)l * 32;   // uniform -> s_load
        const float* tb = table + l * 16;              // uniform -> s_load

        float er[3][3] = {{0,0,0},{0,0,0},{0,0,0}};
        #pragma unroll
        for (int j = 0; j < 8; ++j) {
            float b0 = es[j], b1 = es[8 + j], b2 = es[16 + j];
            float a0 = ed[j], a1 = ed[8 + j], a2 = ed[16 + j];
            er[0][0] = fmaf(a0, b0, er[0][0]);
            er[0][1] = fmaf(a0, b1, er[0][1]);
            er[0][2] = fmaf(a0, b2, er[0][2]);
            er[1][0] = fmaf(a1, b0, er[1][0]);
            er[1][1] = fmaf(a1, b1, er[1][1]);
            er[1][2] = fmaf(a1, b2, er[1][2]);
            er[2][0] = fmaf(a2, b0, er[2][0]);
            er[2][1] = fmaf(a2, b1, er[2][1]);
            er[2][2] = fmaf(a2, b2, er[2][2]);
        }

        float cdot = 0.f;
        #pragma unroll
        for (int f = 0; f < 32; ++f) cdot = fmaf(xf[f], xc[f], cdot);

        size_t idx = (size_t)l * N + n;
        int bp = bestp[idx];
        int a = (bp >> 4) & 3, b = (bp >> 2) & 3, c = bp & 3;

        float e0 = (a == 0) ? er[0][0] : ((a == 1) ? er[0][1] : er[0][2]);
        float e1 = (b == 0) ? er[1][0] : ((b == 1) ? er[1][1] : er[1][2]);
        float e2 = (c == 0) ? er[2][0] : ((c == 1) ? er[2][1] : er[2][2]);
        float bestE = e0 + e1 + e2;

        float n0 = tb[0], n1 = tb[1], n2 = tb[2];
        float C01 = tb[3], C02 = tb[4], C12 = tb[5];
        float la = (a == 0) ? n0 : ((a == 1) ? n1 : n2);
        float lb = (b == 0) ? n0 : ((b == 1) ? n1 : n2);
        float lc = (c == 0) ? n0 : ((c == 1) ? n1 : n2);
        float bestL = fmaf(lenN0, la, fmaf(lenN1, lb, lenN2 * lc));

        int sca = c + a, sab = a + b, sbc = b + c;            // in {1,2,3}
        float Cca = (sca == 1) ? C01 : ((sca == 2) ? C02 : C12);
        float Cab = (sab == 1) ? C01 : ((sab == 2) ? C02 : C12);
        float Cbc = (sbc == 1) ? C01 : ((sbc == 2) ? C02 : C12);
        float bestA = fmaf(angN0, Cca, fmaf(angN1, Cab, angN2 * Cbc));

        float edge_sc = atanf(1.0f / (edsq    + tb[8] - 2.0f * bestE));
        float ang_sc  = atanf(1.0f / (angN_sq + tb[6] - 2.0f * bestA));
        float len_sc  = atanf(1.0f / (lenN_sq + tb[7] - 2.0f * bestL));
        float cen_sc  = atanf(1.0f / (xfsq    + tb[9] - 2.0f * cdot));

        float t1 = len_sc - HPf, t2 = ang_sc - HPf, t4 = cen_sc - HPf, t5 = edge_sc - HPf;
        float h = out[idx] + t1*t1 + t2*t2 + t4*t4 + t5*t5;
        out[idx] = atanf(1.0f / h);
    }
}

extern "C" void kernel_launch(void* const* d_in, const int* in_sizes, int n_in,
                              void* d_out, int out_size, void* d_ws, size_t ws_size,
                              hipStream_t stream)
{
    const float* x_focal    = (const float*)d_in[0];
    const float* p_focal    = (const float*)d_in[1];
    const float* x_neighbor = (const float*)d_in[2];
    const float* p_neighbor = (const float*)d_in[3];
    const float* edge_nei   = (const float*)d_in[4];
    const float* x_center   = (const float*)d_in[5];
    const float* x_support  = (const float*)d_in[6];
    const float* edge_sup   = (const float*)d_in[7];
    const float* p_support  = (const float*)d_in[8];
    float* out = (float*)d_out;

    const int N = in_sizes[0] / 32;                // x_focal is (N, 32)
    const size_t LN = (size_t)L_ * (size_t)N;

    // d_ws layout: [0,4096) table | [4096, 4096+LN) bestp | cnt | worklist
    float* table = (float*)d_ws;
    unsigned char* bestp = (unsigned char*)d_ws + 4096;
    size_t cnt_off = 4096 + ((LN + 15) & ~(size_t)15);
    int* wl_cnt = (int*)((char*)d_ws + cnt_off);
    int* wl     = (int*)((char*)d_ws + cnt_off + 16);
    long cap_l = ((long)ws_size - (long)cnt_off - 16) / 4;
    int wl_cap = cap_l < 0 ? 0 : (cap_l > 2000000 ? 2000000 : (int)cap_l);

    hipMemsetAsync(wl_cnt, 0, sizeof(int), stream);

    setconvP<<<1, 64, 0, stream>>>(x_support, edge_sup, x_center, p_support, table);

    // A: 4 waves/block, each wave 32 n's -> 128 n per block
    const int blocksA = (N + 127) / 128;
    setconvA_mfma<<<blocksA, 256, 0, stream>>>(x_neighbor, x_support, table, out,
                                               bestp, wl_cnt, wl, wl_cap, N);
    setconvA2<<<64, 256, 0, stream>>>(x_neighbor, x_support, out, bestp,
                                      wl_cnt, wl, wl_cap, N);

    dim3 gridB((N + 127) / 128, L_ / LCHUNK);
    setconvB<<<gridB, 128, 0, stream>>>(x_focal, p_focal, p_neighbor, edge_nei,
                                        x_center, edge_sup, table, bestp, out, N);
}

// Round 10
// 175.709 us; speedup vs baseline: 1.0533x; 1.0533x over previous
//
#include <hip/hip_runtime.h>
#include <math.h>

#define L_ 64
#define LCHUNK 16            // l's per block in kernel B (grid.y = 4)
#define HPf 1.57079632679489661923f
#define TIE_THR 4e-3f        // f16-split dot err ~2e-5 << fp32's 4e-4 bound -> same proof

typedef _Float16 half4 __attribute__((ext_vector_type(4)));
typedef float    f32x4 __attribute__((ext_vector_type(4)));

// split fp32 vec4 -> f16 hi + f16 lo (x = hi + lo + O(2^-22 x))
#define CVT4(H, L, V) {                                                       \
    _Float16 h0=(_Float16)(V).x, h1=(_Float16)(V).y,                          \
             h2=(_Float16)(V).z, h3=(_Float16)(V).w;                          \
    (H) = (half4){h0, h1, h2, h3};                                            \
    (L) = (half4){(_Float16)((V).x-(float)h0), (_Float16)((V).y-(float)h1),   \
                  (_Float16)((V).z-(float)h2), (_Float16)((V).w-(float)h3)};  \
}

// ---------------- Kernel P: per-l scalar table (64 threads) ----------------
// table row l (16 floats): [0]n0 [1]n1 [2]n2 [3]C01 [4]C02 [5]C12
//                          [6]angS_sq [7]lenS_sq [8]esq [9]csq [10]ssqf
__global__ __launch_bounds__(64)
void setconvP(const float* __restrict__ x_support,
              const float* __restrict__ edge_sup,
              const float* __restrict__ x_center,
              const float* __restrict__ p_support,
              float* __restrict__ table)
{
    const int l = threadIdx.x;
    if (l >= L_) return;

    const float* xs = x_support + (size_t)l * 96;
    double ssq = 0.0;
    for (int i = 0; i < 96; ++i) { double v = (double)xs[i]; ssq += v * v; }

    const float* es = edge_sup + (size_t)l * 24;
    float esq = 0.f;
    for (int i = 0; i < 24; ++i) esq = fmaf(es[i], es[i], esq);

    const float* xc = x_center + (size_t)l * 32;
    float csq = 0.f;
    for (int i = 0; i < 32; ++i) csq = fmaf(xc[i], xc[i], csq);

    float p0[3], p1[3], p2[3];
    for (int d = 0; d < 3; ++d) {
        p0[d] = p_support[(l * 3 + 0) * 3 + d];
        p1[d] = p_support[(l * 3 + 1) * 3 + d];
        p2[d] = p_support[(l * 3 + 2) * 3 + d];
    }
    float n0 = sqrtf(p0[0]*p0[0] + p0[1]*p0[1] + p0[2]*p0[2]);
    float n1 = sqrtf(p1[0]*p1[0] + p1[1]*p1[1] + p1[2]*p1[2]);
    float n2 = sqrtf(p2[0]*p2[0] + p2[1]*p2[1] + p2[2]*p2[2]);
    float d01 = p0[0]*p1[0] + p0[1]*p1[1] + p0[2]*p1[2];
    float d02 = p0[0]*p2[0] + p0[1]*p2[1] + p0[2]*p2[2];
    float d12 = p1[0]*p2[0] + p1[1]*p2[1] + p1[2]*p2[2];
    float C01 = d01 / fmaxf(n0 * n1, 1e-8f);
    float C02 = d02 / fmaxf(n0 * n2, 1e-8f);
    float C12 = d12 / fmaxf(n1 * n2, 1e-8f);

    float* t = table + l * 16;
    t[0] = n0;  t[1] = n1;  t[2] = n2;
    t[3] = C01; t[4] = C02; t[5] = C12;
    t[6] = C01*C01 + C02*C02 + C12*C12;
    t[7] = n0*n0 + n1*n1 + n2*n2;
    t[8] = esq;
    t[9] = csq;
    t[10] = (float)ssq;
}

// ---------------- Kernel A (MFMA): support argmax + tie worklist ------------
// GEMM view: C[nm][c] = dot(xn[n,m,:], xs[c,:]), M = n*4+m (m=3 zero-pad),
// N' = 192 support rows (12 col-tiles of 16), K = 32 (2 halves of 16).
// SINGLE-WAVE workgroups: the C-shuffle via LDS is wave-private, so with
// 64-thread blocks s_barrier is elided and nothing convoys. Compact LDS
// (only the 3 real rows per 4-row group, stride 13) = 9984 B/block ->
// 16 blocks/CU; with VGPR~104 that's 4 waves/SIMD (2x round-9 TLP).
__global__ __launch_bounds__(64)
void setconvA_mfma(const float* __restrict__ x_neighbor,
                   const float* __restrict__ x_support,
                   const float* __restrict__ table,
                   float* __restrict__ out,
                   unsigned char* __restrict__ bestp,
                   int* __restrict__ wl_cnt,
                   int* __restrict__ wl,
                   int wl_cap,
                   int N)
{
    // col c stores rows {4g+e : e<3} at c*13 + 3g + e  (stride 13: odd -> no
    // systematic bank conflicts; 192*13*4 B = 9984 B)
    __shared__ float clds[192 * 13];

    const int lane = threadIdx.x;
    const int col  = lane & 15;         // A-row / B-col index
    const int kg   = lane >> 4;         // k-group 0..3 (k = 16h + 4kg + e)
    const int n_off = col >> 2;         // A rows: n_local*4 + m
    const int m     = col & 3;          // m==3 -> zero pad row

    const int n_start = blockIdx.x * 32;   // 8 chunks x 4 n per wave

    // ---- B fragments: 12 tiles x 2 k-halves, hi+lo (persistent, ~96 VGPR) ----
    half4 bh[12][2], bl[12][2];
    #pragma unroll
    for (int t = 0; t < 12; ++t) {
        const float* bp = x_support + (size_t)(16 * t + col) * 32 + kg * 4;
        float4 v0 = *(const float4*)bp;
        float4 v1 = *(const float4*)(bp + 16);
        CVT4(bh[t][0], bl[t][0], v0);
        CVT4(bh[t][1], bl[t][1], v1);
    }

    const float4 z4 = make_float4(0.f, 0.f, 0.f, 0.f);

    // prefetch chunk 0's A rows
    float4 pv0, pv1;
    {
        int n_i = n_start + n_off;
        bool ok = (m < 3) && (n_i < N);
        const float* ap = x_neighbor + (size_t)n_i * 96 + m * 32 + kg * 4;
        pv0 = ok ? *(const float4*)ap        : z4;
        pv1 = ok ? *(const float4*)(ap + 16) : z4;
    }

    for (int c8 = 0; c8 < 8; ++c8) {
        const int n_base = n_start + c8 * 4;
        float4 va0 = pv0, va1 = pv1;
        if (c8 < 7) {
            int n_i = n_base + 4 + n_off;
            bool ok = (m < 3) && (n_i < N);
            const float* ap = x_neighbor + (size_t)n_i * 96 + m * 32 + kg * 4;
            pv0 = ok ? *(const float4*)ap        : z4;
            pv1 = ok ? *(const float4*)(ap + 16) : z4;
        }

        // nei_sq: per-lane row partial -> reduce over k-groups, then over m
        float rp = va0.x*va0.x + va0.y*va0.y + va0.z*va0.z + va0.w*va0.w
                 + va1.x*va1.x + va1.y*va1.y + va1.z*va1.z + va1.w*va1.w;
        rp += __shfl_xor(rp, 16);
        rp += __shfl_xor(rp, 32);            // rowsq[row], row = lane&15
        float tq = rp + __shfl_xor(rp, 1);
        float nsq4 = tq + __shfl_xor(tq, 2); // nei_sq of this lane's nibble-n

        // A fragments (hi/lo, 2 k-halves)
        half4 ah0, al0, ah1, al1;
        CVT4(ah0, al0, va0);
        CVT4(ah1, al1, va1);

        // ---- 72 MFMAs: 12 tiles x 2 k-halves x 3 precision passes ----
        f32x4 acc[12] = {};
        #pragma unroll
        for (int t = 0; t < 12; ++t) {
            acc[t] = __builtin_amdgcn_mfma_f32_16x16x16f16(ah0, bh[t][0], acc[t], 0, 0, 0);
            acc[t] = __builtin_amdgcn_mfma_f32_16x16x16f16(al0, bh[t][0], acc[t], 0, 0, 0);
            acc[t] = __builtin_amdgcn_mfma_f32_16x16x16f16(ah0, bl[t][0], acc[t], 0, 0, 0);
            acc[t] = __builtin_amdgcn_mfma_f32_16x16x16f16(ah1, bh[t][1], acc[t], 0, 0, 0);
            acc[t] = __builtin_amdgcn_mfma_f32_16x16x16f16(al1, bh[t][1], acc[t], 0, 0, 0);
            acc[t] = __builtin_amdgcn_mfma_f32_16x16x16f16(ah1, bl[t][1], acc[t], 0, 0, 0);
        }

        // ---- C -> LDS (compact: skip pad row e=3) ----
        #pragma unroll
        for (int t = 0; t < 12; ++t) {
            int base = (16 * t + col) * 13 + 3 * kg;
            clds[base + 0] = acc[t][0];
            clds[base + 1] = acc[t][1];
            clds[base + 2] = acc[t][2];
        }

        __syncthreads();   // single-wave block: elided / lgkmcnt only

        // ---- epilogue: lane <-> (n_local = lane>>4, l = (lane&15)+16*it) ----
        const int nloc = lane >> 4;
        const int n_e  = n_base + nloc;
        const float nei_e = __shfl(nsq4, nloc * 4);

        #pragma unroll
        for (int it = 0; it < 4; ++it) {
            const int l = (lane & 15) + 16 * it;
            // q_k[m] = C[4nloc+m][3l+k] = cr[m][k]
            const int b0i = (3*l + 0) * 13 + 3 * nloc;
            const int b1i = (3*l + 1) * 13 + 3 * nloc;
            const int b2i = (3*l + 2) * 13 + 3 * nloc;
            float q00 = clds[b0i+0], q01 = clds[b0i+1], q02 = clds[b0i+2];
            float q10 = clds[b1i+0], q11 = clds[b1i+1], q12 = clds[b1i+2];
            float q20 = clds[b2i+0], q21 = clds[b2i+1], q22 = clds[b2i+2];

            float c0 = q00 + q11 + q22;   // (0,1,2) -> 6
            float c1 = q00 + q21 + q12;   // (0,2,1) -> 9
            float c2 = q10 + q01 + q22;   // (1,0,2) -> 18
            float c3 = q10 + q21 + q02;   // (1,2,0) -> 24
            float c4 = q20 + q01 + q12;   // (2,0,1) -> 33
            float c5 = q20 + q11 + q02;   // (2,1,0) -> 36

            float b1 = c0, b2 = -3.4e38f; int bpk = 6;
            if (c1 > b1) { b2 = b1; b1 = c1; bpk = 9;  } else if (c1 > b2) b2 = c1;
            if (c2 > b1) { b2 = b1; b1 = c2; bpk = 18; } else if (c2 > b2) b2 = c2;
            if (c3 > b1) { b2 = b1; b1 = c3; bpk = 24; } else if (c3 > b2) b2 = c3;
            if (c4 > b1) { b2 = b1; b1 = c4; bpk = 33; } else if (c4 > b2) b2 = c4;
            if (c5 > b1) { b2 = b1; b1 = c5; bpk = 36; } else if (c5 > b2) b2 = c5;

            if (n_e < N) {
                float ssqf = table[l * 16 + 10];
                float dist = nei_e + ssqf - 2.0f * b1;
                float t3 = atanf(1.0f / dist) - HPf;
                size_t idx = (size_t)l * N + n_e;
                out[idx]   = t3 * t3;
                bestp[idx] = (unsigned char)bpk;
                if (b1 - b2 <= TIE_THR) {
                    int slot = atomicAdd(wl_cnt, 1);
                    if (slot < wl_cap) wl[slot] = (int)idx;
                }
            }
        }
        __syncthreads();   // protect clds reuse across chunks (wave-local)
    }
}

// ---------------- Kernel A2: fp64 tie refinement (worklist) ----------------
__global__ __launch_bounds__(256)
void setconvA2(const float* __restrict__ x_neighbor,
               const float* __restrict__ x_support,
               float* __restrict__ out,
               unsigned char* __restrict__ bestp,
               const int* __restrict__ wl_cnt,
               const int* __restrict__ wl,
               int wl_cap,
               int N)
{
    int cnt = *wl_cnt; if (cnt > wl_cap) cnt = wl_cap;
    const int stride = gridDim.x * blockDim.x;
    for (int i = blockIdx.x * blockDim.x + threadIdx.x; i < cnt; i += stride) {
        const int idx = wl[i];
        const int l = idx / N;
        const int n = idx - l * N;
        const float* xn = x_neighbor + (size_t)n * 96;
        const float* xs = x_support  + (size_t)l * 96;

        double dr[3][3] = {{0,0,0},{0,0,0},{0,0,0}};
        double nei = 0.0, ssq = 0.0;
        for (int f = 0; f < 32; ++f) {
            double a0 = (double)xn[f], a1 = (double)xn[32 + f], a2 = (double)xn[64 + f];
            double b0 = (double)xs[f], b1 = (double)xs[32 + f], b2 = (double)xs[64 + f];
            dr[0][0] += a0 * b0; dr[0][1] += a0 * b1; dr[0][2] += a0 * b2;
            dr[1][0] += a1 * b0; dr[1][1] += a1 * b1; dr[1][2] += a1 * b2;
            dr[2][0] += a2 * b0; dr[2][1] += a2 * b1; dr[2][2] += a2 * b2;
            nei += a0 * a0 + a1 * a1 + a2 * a2;
            ssq += b0 * b0 + b1 * b1 + b2 * b2;
        }
        double d0 = dr[0][0] + dr[1][1] + dr[2][2];
        double d1 = dr[0][0] + dr[1][2] + dr[2][1];
        double d2 = dr[0][1] + dr[1][0] + dr[2][2];
        double d3 = dr[0][1] + dr[1][2] + dr[2][0];
        double d4 = dr[0][2] + dr[1][0] + dr[2][1];
        double d5 = dr[0][2] + dr[1][1] + dr[2][0];
        double db = d0; int bpk = 6;
        if (d1 > db) { db = d1; bpk = 9;  }
        if (d2 > db) { db = d2; bpk = 18; }
        if (d3 > db) { db = d3; bpk = 24; }
        if (d4 > db) { db = d4; bpk = 33; }
        if (d5 > db) { db = d5; bpk = 36; }

        float dist = (float)(nei + (double)((float)ssq) - 2.0 * db);
        float t3 = atanf(1.0f / dist) - HPf;
        out[idx]   = t3 * t3;
        bestp[idx] = (unsigned char)bpk;
    }
}

// ---------------- Kernel B: value-only scores (fp32, SGPR operands) --------
__global__ __launch_bounds__(128)
void setconvB(const float* __restrict__ x_focal,
              const float* __restrict__ p_focal,
              const float* __restrict__ p_neighbor,
              const float* __restrict__ edge_nei,
              const float* __restrict__ x_center,
              const float* __restrict__ edge_sup,
              const float* __restrict__ table,
              const unsigned char* __restrict__ bestp,
              float* __restrict__ out,
              int N)
{
    const int tid = threadIdx.x;
    const int l0  = blockIdx.y * LCHUNK;
    const int n = blockIdx.x * 128 + tid;
    if (n >= N) return;

    float ed[24], xf[32];
    {
        const float4* q = (const float4*)(edge_nei + (size_t)n * 24);
        #pragma unroll
        for (int i = 0; i < 6; ++i) {
            float4 v = q[i];
            ed[4*i+0] = v.x; ed[4*i+1] = v.y; ed[4*i+2] = v.z; ed[4*i+3] = v.w;
        }
        const float4* r = (const float4*)(x_focal + (size_t)n * 32);
        #pragma unroll
        for (int i = 0; i < 8; ++i) {
            float4 v = r[i];
            xf[4*i+0] = v.x; xf[4*i+1] = v.y; xf[4*i+2] = v.z; xf[4*i+3] = v.w;
        }
    }

    float pr[3][3];
    {
        float pf0 = p_focal[(size_t)n*3 + 0];
        float pf1 = p_focal[(size_t)n*3 + 1];
        float pf2 = p_focal[(size_t)n*3 + 2];
        #pragma unroll
        for (int m = 0; m < 3; ++m) {
            pr[m][0] = p_neighbor[(size_t)n*9 + m*3 + 0] - pf0;
            pr[m][1] = p_neighbor[(size_t)n*9 + m*3 + 1] - pf1;
            pr[m][2] = p_neighbor[(size_t)n*9 + m*3 + 2] - pf2;
        }
    }
    float lenN0 = sqrtf(pr[0][0]*pr[0][0] + pr[0][1]*pr[0][1] + pr[0][2]*pr[0][2]);
    float lenN1 = sqrtf(pr[1][0]*pr[1][0] + pr[1][1]*pr[1][1] + pr[1][2]*pr[1][2]);
    float lenN2 = sqrtf(pr[2][0]*pr[2][0] + pr[2][1]*pr[2][1] + pr[2][2]*pr[2][2]);
    float angN0 = (pr[2][0]*pr[0][0] + pr[2][1]*pr[0][1] + pr[2][2]*pr[0][2]) / fmaxf(lenN2*lenN0, 1e-8f);
    float angN1 = (pr[0][0]*pr[1][0] + pr[0][1]*pr[1][1] + pr[0][2]*pr[1][2]) / fmaxf(lenN0*lenN1, 1e-8f);
    float angN2 = (pr[1][0]*pr[2][0] + pr[1][1]*pr[2][1] + pr[1][2]*pr[2][2]) / fmaxf(lenN1*lenN2, 1e-8f);
    float angN_sq = angN0*angN0 + angN1*angN1 + angN2*angN2;
    float lenN_sq = lenN0*lenN0 + lenN1*lenN1 + lenN2*lenN2;

    float edsq = 0.f, xfsq = 0.f;
    #pragma unroll
    for (int i = 0; i < 24; ++i) edsq = fmaf(ed[i], ed[i], edsq);
    #pragma unroll
    for (int i = 0; i < 32; ++i) xfsq = fmaf(xf[i], xf[i], xfsq);

    for (int ll = 0; ll < LCHUNK; ++ll) {
        const int l = l0 + ll;
        const float* es = edge_sup + (size_t)l * 24;   // uniform -> s_load
        const float* xc = x_center + (size_t)l * 32;   // uniform -> s_load
        const float* tb = table + l * 16;              // uniform -> s_load

        float er[3][3] = {{0,0,0},{0,0,0},{0,0,0}};
        #pragma unroll
        for (int j = 0; j < 8; ++j) {
            float b0 = es[j], b1 = es[8 + j], b2 = es[16 + j];
            float a0 = ed[j], a1 = ed[8 + j], a2 = ed[16 + j];
            er[0][0] = fmaf(a0, b0, er[0][0]);
            er[0][1] = fmaf(a0, b1, er[0][1]);
            er[0][2] = fmaf(a0, b2, er[0][2]);
            er[1][0] = fmaf(a1, b0, er[1][0]);
            er[1][1] = fmaf(a1, b1, er[1][1]);
            er[1][2] = fmaf(a1, b2, er[1][2]);
            er[2][0] = fmaf(a2, b0, er[2][0]);
            er[2][1] = fmaf(a2, b1, er[2][1]);
            er[2][2] = fmaf(a2, b2, er[2][2]);
        }

        float cdot = 0.f;
        #pragma unroll
        for (int f = 0; f < 32; ++f) cdot = fmaf(xf[f], xc[f], cdot);

        size_t idx = (size_t)l * N + n;
        int bp = bestp[idx];
        int a = (bp >> 4) & 3, b = (bp >> 2) & 3, c = bp & 3;

        float e0 = (a == 0) ? er[0][0] : ((a == 1) ? er[0][1] : er[0][2]);
        float e1 = (b == 0) ? er[1][0] : ((b == 1) ? er[1][1] : er[1][2]);
        float e2 = (c == 0) ? er[2][0] : ((c == 1) ? er[2][1] : er[2][2]);
        float bestE = e0 + e1 + e2;

        float n0 = tb[0], n1 = tb[1], n2 = tb[2];
        float C01 = tb[3], C02 = tb[4], C12 = tb[5];
        float la = (a == 0) ? n0 : ((a == 1) ? n1 : n2);
        float lb = (b == 0) ? n0 : ((b == 1) ? n1 : n2);
        float lc = (c == 0) ? n0 : ((c == 1) ? n1 : n2);
        float bestL = fmaf(lenN0, la, fmaf(lenN1, lb, lenN2 * lc));

        int sca = c + a, sab = a + b, sbc = b + c;            // in {1,2,3}
        float Cca = (sca == 1) ? C01 : ((sca == 2) ? C02 : C12);
        float Cab = (sab == 1) ? C01 : ((sab == 2) ? C02 : C12);
        float Cbc = (sbc == 1) ? C01 : ((sbc == 2) ? C02 : C12);
        float bestA = fmaf(angN0, Cca, fmaf(angN1, Cab, angN2 * Cbc));

        float edge_sc = atanf(1.0f / (edsq    + tb[8] - 2.0f * bestE));
        float ang_sc  = atanf(1.0f / (angN_sq + tb[6] - 2.0f * bestA));
        float len_sc  = atanf(1.0f / (lenN_sq + tb[7] - 2.0f * bestL));
        float cen_sc  = atanf(1.0f / (xfsq    + tb[9] - 2.0f * cdot));

        float t1 = len_sc - HPf, t2 = ang_sc - HPf, t4 = cen_sc - HPf, t5 = edge_sc - HPf;
        float h = out[idx] + t1*t1 + t2*t2 + t4*t4 + t5*t5;
        out[idx] = atanf(1.0f / h);
    }
}

extern "C" void kernel_launch(void* const* d_in, const int* in_sizes, int n_in,
                              void* d_out, int out_size, void* d_ws, size_t ws_size,
                              hipStream_t stream)
{
    const float* x_focal    = (const float*)d_in[0];
    const float* p_focal    = (const float*)d_in[1];
    const float* x_neighbor = (const float*)d_in[2];
    const float* p_neighbor = (const float*)d_in[3];
    const float* edge_nei   = (const float*)d_in[4];
    const float* x_center   = (const float*)d_in[5];
    const float* x_support  = (const float*)d_in[6];
    const float* edge_sup   = (const float*)d_in[7];
    const float* p_support  = (const float*)d_in[8];
    float* out = (float*)d_out;

    const int N = in_sizes[0] / 32;                // x_focal is (N, 32)
    const size_t LN = (size_t)L_ * (size_t)N;

    // d_ws layout: [0,4096) table | [4096, 4096+LN) bestp | cnt | worklist
    float* table = (float*)d_ws;
    unsigned char* bestp = (unsigned char*)d_ws + 4096;
    size_t cnt_off = 4096 + ((LN + 15) & ~(size_t)15);
    int* wl_cnt = (int*)((char*)d_ws + cnt_off);
    int* wl     = (int*)((char*)d_ws + cnt_off + 16);
    long cap_l = ((long)ws_size - (long)cnt_off - 16) / 4;
    int wl_cap = cap_l < 0 ? 0 : (cap_l > 2000000 ? 2000000 : (int)cap_l);

    hipMemsetAsync(wl_cnt, 0, sizeof(int), stream);

    setconvP<<<1, 64, 0, stream>>>(x_support, edge_sup, x_center, p_support, table);

    // A: single-wave blocks, each wave 32 n's
    const int blocksA = (N + 31) / 32;
    setconvA_mfma<<<blocksA, 64, 0, stream>>>(x_neighbor, x_support, table, out,
                                              bestp, wl_cnt, wl, wl_cap, N);
    setconvA2<<<64, 256, 0, stream>>>(x_neighbor, x_support, out, bestp,
                                      wl_cnt, wl, wl_cap, N);

    dim3 gridB((N + 127) / 128, L_ / LCHUNK);
    setconvB<<<gridB, 128, 0, stream>>>(x_focal, p_focal, p_neighbor, edge_nei,
                                        x_center, edge_sup, table, bestp, out, N);
}

// Round 11
// 169.447 us; speedup vs baseline: 1.0922x; 1.0370x over previous
//
#include <hip/hip_runtime.h>
#include <math.h>

#define L_ 64
#define LCHUNK 16            // l's per block in kernel B (grid.y = 4)
#define HPf 1.57079632679489661923f
#define TIE_THR 4e-3f        // f16-split dot err ~2e-5 << fp32's 4e-4 bound

typedef _Float16 half4 __attribute__((ext_vector_type(4)));
typedef float    f32x4 __attribute__((ext_vector_type(4)));

// split fp32 vec4 -> f16 hi + f16 lo (x = hi + lo + O(2^-22 x))
#define CVT4(H, L, V) {                                                       \
    _Float16 h0=(_Float16)(V).x, h1=(_Float16)(V).y,                          \
             h2=(_Float16)(V).z, h3=(_Float16)(V).w;                          \
    (H) = (half4){h0, h1, h2, h3};                                            \
    (L) = (half4){(_Float16)((V).x-(float)h0), (_Float16)((V).y-(float)h1),   \
                  (_Float16)((V).z-(float)h2), (_Float16)((V).w-(float)h3)};  \
}

// 6 MFMA accumulation steps for one (u,k) tile pair -> acc (same op order
// as rounds 9/10 -> bit-identical C values)
#define MFMA6(ACC, T)                                                          \
    ACC = __builtin_amdgcn_mfma_f32_16x16x16f16(ah0, bh[T][0], ACC, 0, 0, 0); \
    ACC = __builtin_amdgcn_mfma_f32_16x16x16f16(al0, bh[T][0], ACC, 0, 0, 0); \
    ACC = __builtin_amdgcn_mfma_f32_16x16x16f16(ah0, bl[T][0], ACC, 0, 0, 0); \
    ACC = __builtin_amdgcn_mfma_f32_16x16x16f16(ah1, bh[T][1], ACC, 0, 0, 0); \
    ACC = __builtin_amdgcn_mfma_f32_16x16x16f16(al1, bh[T][1], ACC, 0, 0, 0); \
    ACC = __builtin_amdgcn_mfma_f32_16x16x16f16(ah1, bl[T][1], ACC, 0, 0, 0);

// ---------------- Kernel P: per-l scalar table (64 threads) ----------------
// table row l (16 floats): [0]n0 [1]n1 [2]n2 [3]C01 [4]C02 [5]C12
//                          [6]angS_sq [7]lenS_sq [8]esq [9]csq [10]ssqf
__global__ __launch_bounds__(64)
void setconvP(const float* __restrict__ x_support,
              const float* __restrict__ edge_sup,
              const float* __restrict__ x_center,
              const float* __restrict__ p_support,
              float* __restrict__ table)
{
    const int l = threadIdx.x;
    if (l >= L_) return;

    const float* xs = x_support + (size_t)l * 96;
    double ssq = 0.0;
    for (int i = 0; i < 96; ++i) { double v = (double)xs[i]; ssq += v * v; }

    const float* es = edge_sup + (size_t)l * 24;
    float esq = 0.f;
    for (int i = 0; i < 24; ++i) esq = fmaf(es[i], es[i], esq);

    const float* xc = x_center + (size_t)l * 32;
    float csq = 0.f;
    for (int i = 0; i < 32; ++i) csq = fmaf(xc[i], xc[i], csq);

    float p0[3], p1[3], p2[3];
    for (int d = 0; d < 3; ++d) {
        p0[d] = p_support[(l * 3 + 0) * 3 + d];
        p1[d] = p_support[(l * 3 + 1) * 3 + d];
        p2[d] = p_support[(l * 3 + 2) * 3 + d];
    }
    float n0 = sqrtf(p0[0]*p0[0] + p0[1]*p0[1] + p0[2]*p0[2]);
    float n1 = sqrtf(p1[0]*p1[0] + p1[1]*p1[1] + p1[2]*p1[2]);
    float n2 = sqrtf(p2[0]*p2[0] + p2[1]*p2[1] + p2[2]*p2[2]);
    float d01 = p0[0]*p1[0] + p0[1]*p1[1] + p0[2]*p1[2];
    float d02 = p0[0]*p2[0] + p0[1]*p2[1] + p0[2]*p2[2];
    float d12 = p1[0]*p2[0] + p1[1]*p2[1] + p1[2]*p2[2];
    float C01 = d01 / fmaxf(n0 * n1, 1e-8f);
    float C02 = d02 / fmaxf(n0 * n2, 1e-8f);
    float C12 = d12 / fmaxf(n1 * n2, 1e-8f);

    float* t = table + l * 16;
    t[0] = n0;  t[1] = n1;  t[2] = n2;
    t[3] = C01; t[4] = C02; t[5] = C12;
    t[6] = C01*C01 + C02*C02 + C12*C12;
    t[7] = n0*n0 + n1*n1 + n2*n2;
    t[8] = esq;
    t[9] = csq;
    t[10] = (float)ssq;
}

// ---------------- Kernel A (MFMA): support argmax + tie worklist ------------
// GEMM view: C[nm][c] = dot(xn[n,m,:], xs[c,:]), M-rows = 4*n_loc + m.
// PERMUTED B assignment: tile t=3u+k, B-col j holds support row 48u+3j+k
// (bijection onto 0..191). C layout (col=lane&15, row=4kg+reg) then puts the
// ENTIRE 3x3 dot matrix of cell (n = n_base+kg, l = 16u+j) into one lane's
// accumulators: cr[m][k] = acc_{3u+k}[m]. Argmax fully in registers ->
// zero LDS, zero barriers, no C round-trip.
__global__ __launch_bounds__(64)
void setconvA_mfma(const float* __restrict__ x_neighbor,
                   const float* __restrict__ x_support,
                   const float* __restrict__ table,
                   float* __restrict__ out,
                   unsigned char* __restrict__ bestp,
                   int* __restrict__ wl_cnt,
                   int* __restrict__ wl,
                   int wl_cap,
                   int N)
{
    const int lane = threadIdx.x;
    const int j    = lane & 15;         // A-row index / B-col index
    const int kg   = lane >> 4;         // k-group 0..3 (k = 16h + 4kg + e)
    const int n_off = j >> 2;           // A rows: n_local*4 + m
    const int m     = j & 3;            // m==3 -> zero pad row

    const int n_start = blockIdx.x * 32;   // 8 chunks x 4 n per wave

    // ---- B fragments: t=3u+k, col j <-> support row 48u+3j+k ----
    half4 bh[12][2], bl[12][2];
    #pragma unroll
    for (int u = 0; u < 4; ++u)
        #pragma unroll
        for (int k = 0; k < 3; ++k) {
            const float* bp = x_support + (size_t)(48*u + 3*j + k) * 32 + kg * 4;
            float4 v0 = *(const float4*)bp;
            float4 v1 = *(const float4*)(bp + 16);
            CVT4(bh[3*u+k][0], bl[3*u+k][0], v0);
            CVT4(bh[3*u+k][1], bl[3*u+k][1], v1);
        }

    // per-lane sup_sq for this lane's l's (l = 16u + j), hoisted
    float ssq_u[4];
    #pragma unroll
    for (int u = 0; u < 4; ++u) ssq_u[u] = table[(16*u + j) * 16 + 10];

    const float4 z4 = make_float4(0.f, 0.f, 0.f, 0.f);

    // prefetch chunk 0's A rows
    float4 pv0, pv1;
    {
        int n_i = n_start + n_off;
        bool ok = (m < 3) && (n_i < N);
        const float* ap = x_neighbor + (size_t)n_i * 96 + m * 32 + kg * 4;
        pv0 = ok ? *(const float4*)ap        : z4;
        pv1 = ok ? *(const float4*)(ap + 16) : z4;
    }

    for (int c8 = 0; c8 < 8; ++c8) {
        const int n_base = n_start + c8 * 4;
        float4 va0 = pv0, va1 = pv1;
        if (c8 < 7) {
            int n_i = n_base + 4 + n_off;
            bool ok = (m < 3) && (n_i < N);
            const float* ap = x_neighbor + (size_t)n_i * 96 + m * 32 + kg * 4;
            pv0 = ok ? *(const float4*)ap        : z4;
            pv1 = ok ? *(const float4*)(ap + 16) : z4;
        }

        // nei_sq: identical reduction order to rounds 9/10 (bit-identical)
        float rp = va0.x*va0.x + va0.y*va0.y + va0.z*va0.z + va0.w*va0.w
                 + va1.x*va1.x + va1.y*va1.y + va1.z*va1.z + va1.w*va1.w;
        rp += __shfl_xor(rp, 16);
        rp += __shfl_xor(rp, 32);            // rowsq[row], row = lane&15
        float tq = rp + __shfl_xor(rp, 1);
        float nsq4 = tq + __shfl_xor(tq, 2); // nei_sq of nibble n = (lane&15)>>2

        // A fragments (hi/lo, 2 k-halves)
        half4 ah0, al0, ah1, al1;
        CVT4(ah0, al0, va0);
        CVT4(ah1, al1, va1);

        const int n_e  = n_base + kg;        // this lane's n for ALL its cells
        const float nei_e = __shfl(nsq4, kg * 4);
        const bool nok = (n_e < N);

        #pragma unroll
        for (int u = 0; u < 4; ++u) {
            // 18 MFMAs -> full 3x3 dot matrix of cell (n_e, l=16u+j)
            f32x4 a0 = {}, a1 = {}, a2 = {};
            MFMA6(a0, 3*u + 0)
            MFMA6(a1, 3*u + 1)
            MFMA6(a2, 3*u + 2)

            // cr[m][k] = a_k[m]; perm sums in the SAME add order as R10
            float c0 = a0[0] + a1[1] + a2[2];   // (0,1,2) -> 6
            float c1 = a0[0] + a2[1] + a1[2];   // (0,2,1) -> 9
            float c2 = a1[0] + a0[1] + a2[2];   // (1,0,2) -> 18
            float c3 = a1[0] + a2[1] + a0[2];   // (1,2,0) -> 24
            float c4 = a2[0] + a0[1] + a1[2];   // (2,0,1) -> 33
            float c5 = a2[0] + a1[1] + a0[2];   // (2,1,0) -> 36

            float b1 = c0, b2 = -3.4e38f; int bpk = 6;
            if (c1 > b1) { b2 = b1; b1 = c1; bpk = 9;  } else if (c1 > b2) b2 = c1;
            if (c2 > b1) { b2 = b1; b1 = c2; bpk = 18; } else if (c2 > b2) b2 = c2;
            if (c3 > b1) { b2 = b1; b1 = c3; bpk = 24; } else if (c3 > b2) b2 = c3;
            if (c4 > b1) { b2 = b1; b1 = c4; bpk = 33; } else if (c4 > b2) b2 = c4;
            if (c5 > b1) { b2 = b1; b1 = c5; bpk = 36; } else if (c5 > b2) b2 = c5;

            if (nok) {
                float dist = nei_e + ssq_u[u] - 2.0f * b1;
                float t3 = atanf(1.0f / dist) - HPf;
                size_t idx = (size_t)(16*u + j) * N + n_e;
                out[idx]   = t3 * t3;
                bestp[idx] = (unsigned char)bpk;
                if (b1 - b2 <= TIE_THR) {
                    int slot = atomicAdd(wl_cnt, 1);
                    if (slot < wl_cap) wl[slot] = (int)idx;
                }
            }
        }
    }
}

// ---------------- Kernel A2: fp64 tie refinement (worklist) ----------------
__global__ __launch_bounds__(256)
void setconvA2(const float* __restrict__ x_neighbor,
               const float* __restrict__ x_support,
               float* __restrict__ out,
               unsigned char* __restrict__ bestp,
               const int* __restrict__ wl_cnt,
               const int* __restrict__ wl,
               int wl_cap,
               int N)
{
    int cnt = *wl_cnt; if (cnt > wl_cap) cnt = wl_cap;
    const int stride = gridDim.x * blockDim.x;
    for (int i = blockIdx.x * blockDim.x + threadIdx.x; i < cnt; i += stride) {
        const int idx = wl[i];
        const int l = idx / N;
        const int n = idx - l * N;
        const float* xn = x_neighbor + (size_t)n * 96;
        const float* xs = x_support  + (size_t)l * 96;

        double dr[3][3] = {{0,0,0},{0,0,0},{0,0,0}};
        double nei = 0.0, ssq = 0.0;
        for (int f = 0; f < 32; ++f) {
            double a0 = (double)xn[f], a1 = (double)xn[32 + f], a2 = (double)xn[64 + f];
            double b0 = (double)xs[f], b1 = (double)xs[32 + f], b2 = (double)xs[64 + f];
            dr[0][0] += a0 * b0; dr[0][1] += a0 * b1; dr[0][2] += a0 * b2;
            dr[1][0] += a1 * b0; dr[1][1] += a1 * b1; dr[1][2] += a1 * b2;
            dr[2][0] += a2 * b0; dr[2][1] += a2 * b1; dr[2][2] += a2 * b2;
            nei += a0 * a0 + a1 * a1 + a2 * a2;
            ssq += b0 * b0 + b1 * b1 + b2 * b2;
        }
        double d0 = dr[0][0] + dr[1][1] + dr[2][2];
        double d1 = dr[0][0] + dr[1][2] + dr[2][1];
        double d2 = dr[0][1] + dr[1][0] + dr[2][2];
        double d3 = dr[0][1] + dr[1][2] + dr[2][0];
        double d4 = dr[0][2] + dr[1][0] + dr[2][1];
        double d5 = dr[0][2] + dr[1][1] + dr[2][0];
        double db = d0; int bpk = 6;
        if (d1 > db) { db = d1; bpk = 9;  }
        if (d2 > db) { db = d2; bpk = 18; }
        if (d3 > db) { db = d3; bpk = 24; }
        if (d4 > db) { db = d4; bpk = 33; }
        if (d5 > db) { db = d5; bpk = 36; }

        float dist = (float)(nei + (double)((float)ssq) - 2.0 * db);
        float t3 = atanf(1.0f / dist) - HPf;
        out[idx]   = t3 * t3;
        bestp[idx] = (unsigned char)bpk;
    }
}

// ---------------- Kernel B: value-only scores (fp32, SGPR operands) --------
__global__ __launch_bounds__(128)
void setconvB(const float* __restrict__ x_focal,
              const float* __restrict__ p_focal,
              const float* __restrict__ p_neighbor,
              const float* __restrict__ edge_nei,
              const float* __restrict__ x_center,
              const float* __restrict__ edge_sup,
              const float* __restrict__ table,
              const unsigned char* __restrict__ bestp,
              float* __restrict__ out,
              int N)
{
    const int tid = threadIdx.x;
    const int l0  = blockIdx.y * LCHUNK;
    const int n = blockIdx.x * 128 + tid;
    if (n >= N) return;

    float ed[24], xf[32];
    {
        const float4* q = (const float4*)(edge_nei + (size_t)n * 24);
        #pragma unroll
        for (int i = 0; i < 6; ++i) {
            float4 v = q[i];
            ed[4*i+0] = v.x; ed[4*i+1] = v.y; ed[4*i+2] = v.z; ed[4*i+3] = v.w;
        }
        const float4* r = (const float4*)(x_focal + (size_t)n * 32);
        #pragma unroll
        for (int i = 0; i < 8; ++i) {
            float4 v = r[i];
            xf[4*i+0] = v.x; xf[4*i+1] = v.y; xf[4*i+2] = v.z; xf[4*i+3] = v.w;
        }
    }

    float pr[3][3];
    {
        float pf0 = p_focal[(size_t)n*3 + 0];
        float pf1 = p_focal[(size_t)n*3 + 1];
        float pf2 = p_focal[(size_t)n*3 + 2];
        #pragma unroll
        for (int m = 0; m < 3; ++m) {
            pr[m][0] = p_neighbor[(size_t)n*9 + m*3 + 0] - pf0;
            pr[m][1] = p_neighbor[(size_t)n*9 + m*3 + 1] - pf1;
            pr[m][2] = p_neighbor[(size_t)n*9 + m*3 + 2] - pf2;
        }
    }
    float lenN0 = sqrtf(pr[0][0]*pr[0][0] + pr[0][1]*pr[0][1] + pr[0][2]*pr[0][2]);
    float lenN1 = sqrtf(pr[1][0]*pr[1][0] + pr[1][1]*pr[1][1] + pr[1][2]*pr[1][2]);
    float lenN2 = sqrtf(pr[2][0]*pr[2][0] + pr[2][1]*pr[2][1] + pr[2][2]*pr[2][2]);
    float angN0 = (pr[2][0]*pr[0][0] + pr[2][1]*pr[0][1] + pr[2][2]*pr[0][2]) / fmaxf(lenN2*lenN0, 1e-8f);
    float angN1 = (pr[0][0]*pr[1][0] + pr[0][1]*pr[1][1] + pr[0][2]*pr[1][2]) / fmaxf(lenN0*lenN1, 1e-8f);
    float angN2 = (pr[1][0]*pr[2][0] + pr[1][1]*pr[2][1] + pr[1][2]*pr[2][2]) / fmaxf(lenN1*lenN2, 1e-8f);
    float angN_sq = angN0*angN0 + angN1*angN1 + angN2*angN2;
    float lenN_sq = lenN0*lenN0 + lenN1*lenN1 + lenN2*lenN2;

    float edsq = 0.f, xfsq = 0.f;
    #pragma unroll
    for (int i = 0; i < 24; ++i) edsq = fmaf(ed[i], ed[i], edsq);
    #pragma unroll
    for (int i = 0; i < 32; ++i) xfsq = fmaf(xf[i], xf[i], xfsq);

    for (int ll = 0; ll < LCHUNK; ++ll) {
        const int l = l0 + ll;
        const float* es = edge_sup + (size_t)l * 24;   // uniform -> s_load
        const float* xc = x_center + (size_t)l * 32;   // uniform -> s_load
        const float* tb = table + l * 16;              // uniform -> s_load

        float er[3][3] = {{0,0,0},{0,0,0},{0,0,0}};
        #pragma unroll
        for (int jj = 0; jj < 8; ++jj) {
            float b0 = es[jj], b1 = es[8 + jj], b2 = es[16 + jj];
            float a0 = ed[jj], a1 = ed[8 + jj], a2 = ed[16 + jj];
            er[0][0] = fmaf(a0, b0, er[0][0]);
            er[0][1] = fmaf(a0, b1, er[0][1]);
            er[0][2] = fmaf(a0, b2, er[0][2]);
            er[1][0] = fmaf(a1, b0, er[1][0]);
            er[1][1] = fmaf(a1, b1, er[1][1]);
            er[1][2] = fmaf(a1, b2, er[1][2]);
            er[2][0] = fmaf(a2, b0, er[2][0]);
            er[2][1] = fmaf(a2, b1, er[2][1]);
            er[2][2] = fmaf(a2, b2, er[2][2]);
        }

        float cdot = 0.f;
        #pragma unroll
        for (int f = 0; f < 32; ++f) cdot = fmaf(xf[f], xc[f], cdot);

        size_t idx = (size_t)l * N + n;
        int bp = bestp[idx];
        int a = (bp >> 4) & 3, b = (bp >> 2) & 3, c = bp & 3;

        float e0 = (a == 0) ? er[0][0] : ((a == 1) ? er[0][1] : er[0][2]);
        float e1 = (b == 0) ? er[1][0] : ((b == 1) ? er[1][1] : er[1][2]);
        float e2 = (c == 0) ? er[2][0] : ((c == 1) ? er[2][1] : er[2][2]);
        float bestE = e0 + e1 + e2;

        float n0 = tb[0], n1 = tb[1], n2 = tb[2];
        float C01 = tb[3], C02 = tb[4], C12 = tb[5];
        float la = (a == 0) ? n0 : ((a == 1) ? n1 : n2);
        float lb = (b == 0) ? n0 : ((b == 1) ? n1 : n2);
        float lc = (c == 0) ? n0 : ((c == 1) ? n1 : n2);
        float bestL = fmaf(lenN0, la, fmaf(lenN1, lb, lenN2 * lc));

        int sca = c + a, sab = a + b, sbc = b + c;            // in {1,2,3}
        float Cca = (sca == 1) ? C01 : ((sca == 2) ? C02 : C12);
        float Cab = (sab == 1) ? C01 : ((sab == 2) ? C02 : C12);
        float Cbc = (sbc == 1) ? C01 : ((sbc == 2) ? C02 : C12);
        float bestA = fmaf(angN0, Cca, fmaf(angN1, Cab, angN2 * Cbc));

        float edge_sc = atanf(1.0f / (edsq    + tb[8] - 2.0f * bestE));
        float ang_sc  = atanf(1.0f / (angN_sq + tb[6] - 2.0f * bestA));
        float len_sc  = atanf(1.0f / (lenN_sq + tb[7] - 2.0f * bestL));
        float cen_sc  = atanf(1.0f / (xfsq    + tb[9] - 2.0f * cdot));

        float t1 = len_sc - HPf, t2 = ang_sc - HPf, t4 = cen_sc - HPf, t5 = edge_sc - HPf;
        float h = out[idx] + t1*t1 + t2*t2 + t4*t4 + t5*t5;
        out[idx] = atanf(1.0f / h);
    }
}

extern "C" void kernel_launch(void* const* d_in, const int* in_sizes, int n_in,
                              void* d_out, int out_size, void* d_ws, size_t ws_size,
                              hipStream_t stream)
{
    const float* x_focal    = (const float*)d_in[0];
    const float* p_focal    = (const float*)d_in[1];
    const float* x_neighbor = (const float*)d_in[2];
    const float* p_neighbor = (const float*)d_in[3];
    const float* edge_nei   = (const float*)d_in[4];
    const float* x_center   = (const float*)d_in[5];
    const float* x_support  = (const float*)d_in[6];
    const float* edge_sup   = (const float*)d_in[7];
    const float* p_support  = (const float*)d_in[8];
    float* out = (float*)d_out;

    const int N = in_sizes[0] / 32;                // x_focal is (N, 32)
    const size_t LN = (size_t)L_ * (size_t)N;

    // d_ws layout: [0,4096) table | [4096, 4096+LN) bestp | cnt | worklist
    float* table = (float*)d_ws;
    unsigned char* bestp = (unsigned char*)d_ws + 4096;
    size_t cnt_off = 4096 + ((LN + 15) & ~(size_t)15);
    int* wl_cnt = (int*)((char*)d_ws + cnt_off);
    int* wl     = (int*)((char*)d_ws + cnt_off + 16);
    long cap_l = ((long)ws_size - (long)cnt_off - 16) / 4;
    int wl_cap = cap_l < 0 ? 0 : (cap_l > 2000000 ? 2000000 : (int)cap_l);

    hipMemsetAsync(wl_cnt, 0, sizeof(int), stream);

    setconvP<<<1, 64, 0, stream>>>(x_support, edge_sup, x_center, p_support, table);

    // A: single-wave blocks, each wave 32 n's
    const int blocksA = (N + 31) / 32;
    setconvA_mfma<<<blocksA, 64, 0, stream>>>(x_neighbor, x_support, table, out,
                                              bestp, wl_cnt, wl, wl_cap, N);
    setconvA2<<<64, 256, 0, stream>>>(x_neighbor, x_support, out, bestp,
                                      wl_cnt, wl, wl_cap, N);

    dim3 gridB((N + 127) / 128, L_ / LCHUNK);
    setconvB<<<gridB, 128, 0, stream>>>(x_focal, p_focal, p_neighbor, edge_nei,
                                        x_center, edge_sup, table, bestp, out, N);
}

// Round 12
// 157.824 us; speedup vs baseline: 1.1726x; 1.0737x over previous
//
#include <hip/hip_runtime.h>
#include <math.h>

#define L_ 64
#define LCHUNK 16            // l's per block in kernel B (grid.y = 4)
#define HPf 1.57079632679489661923f
#define TIE_THR 4e-3f        // f16-split dot err ~2e-5 << fp32's 4e-4 bound

typedef _Float16 half4 __attribute__((ext_vector_type(4)));
typedef float    f32x4 __attribute__((ext_vector_type(4)));

// split fp32 vec4 -> f16 hi + f16 lo (x = hi + lo + O(2^-22 x))
#define CVT4(H, L, V) {                                                       \
    _Float16 h0=(_Float16)(V).x, h1=(_Float16)(V).y,                          \
             h2=(_Float16)(V).z, h3=(_Float16)(V).w;                          \
    (H) = (half4){h0, h1, h2, h3};                                            \
    (L) = (half4){(_Float16)((V).x-(float)h0), (_Float16)((V).y-(float)h1),   \
                  (_Float16)((V).z-(float)h2), (_Float16)((V).w-(float)h3)};  \
}

// 6 MFMA accumulation steps for one tile -> acc (same op order as R9-R11
// -> bit-identical C values -> identical argmax)
#define MFMA6(ACC, T)                                                          \
    ACC = __builtin_amdgcn_mfma_f32_16x16x16f16(ah0, bh[T][0], ACC, 0, 0, 0); \
    ACC = __builtin_amdgcn_mfma_f32_16x16x16f16(al0, bh[T][0], ACC, 0, 0, 0); \
    ACC = __builtin_amdgcn_mfma_f32_16x16x16f16(ah0, bl[T][0], ACC, 0, 0, 0); \
    ACC = __builtin_amdgcn_mfma_f32_16x16x16f16(ah1, bh[T][1], ACC, 0, 0, 0); \
    ACC = __builtin_amdgcn_mfma_f32_16x16x16f16(al1, bh[T][1], ACC, 0, 0, 0); \
    ACC = __builtin_amdgcn_mfma_f32_16x16x16f16(ah1, bl[T][1], ACC, 0, 0, 0);

// ---------------- Kernel P: per-l scalar table (64 threads) ----------------
__global__ __launch_bounds__(64)
void setconvP(const float* __restrict__ x_support,
              const float* __restrict__ edge_sup,
              const float* __restrict__ x_center,
              const float* __restrict__ p_support,
              float* __restrict__ table)
{
    const int l = threadIdx.x;
    if (l >= L_) return;

    const float* xs = x_support + (size_t)l * 96;
    double ssq = 0.0;
    for (int i = 0; i < 96; ++i) { double v = (double)xs[i]; ssq += v * v; }

    const float* es = edge_sup + (size_t)l * 24;
    float esq = 0.f;
    for (int i = 0; i < 24; ++i) esq = fmaf(es[i], es[i], esq);

    const float* xc = x_center + (size_t)l * 32;
    float csq = 0.f;
    for (int i = 0; i < 32; ++i) csq = fmaf(xc[i], xc[i], csq);

    float p0[3], p1[3], p2[3];
    for (int d = 0; d < 3; ++d) {
        p0[d] = p_support[(l * 3 + 0) * 3 + d];
        p1[d] = p_support[(l * 3 + 1) * 3 + d];
        p2[d] = p_support[(l * 3 + 2) * 3 + d];
    }
    float n0 = sqrtf(p0[0]*p0[0] + p0[1]*p0[1] + p0[2]*p0[2]);
    float n1 = sqrtf(p1[0]*p1[0] + p1[1]*p1[1] + p1[2]*p1[2]);
    float n2 = sqrtf(p2[0]*p2[0] + p2[1]*p2[1] + p2[2]*p2[2]);
    float d01 = p0[0]*p1[0] + p0[1]*p1[1] + p0[2]*p1[2];
    float d02 = p0[0]*p2[0] + p0[1]*p2[1] + p0[2]*p2[2];
    float d12 = p1[0]*p2[0] + p1[1]*p2[1] + p1[2]*p2[2];
    float C01 = d01 / fmaxf(n0 * n1, 1e-8f);
    float C02 = d02 / fmaxf(n0 * n2, 1e-8f);
    float C12 = d12 / fmaxf(n1 * n2, 1e-8f);

    float* t = table + l * 16;
    t[0] = n0;  t[1] = n1;  t[2] = n2;
    t[3] = C01; t[4] = C02; t[5] = C12;
    t[6] = C01*C01 + C02*C02 + C12*C12;
    t[7] = n0*n0 + n1*n1 + n2*n2;
    t[8] = esq;
    t[9] = csq;
    t[10] = (float)ssq;
}

// ---------------- Kernel A (MFMA): support argmax + tie worklist ------------
// L-SPLIT: gridDim.y = 2, each block owns u-groups {2*by, 2*by+1} (32 l's).
// B-fragments halve to 6 tiles (48 VGPRs) -> VGPR stays under the 128-reg /
// 4-waves-per-SIMD cap while the grid doubles to 6.1 waves/SIMD demand
// (R11 was grid-limited at 3). Permuted-B register-resident argmax as R11.
__global__ __launch_bounds__(64)
void setconvA_mfma(const float* __restrict__ x_neighbor,
                   const float* __restrict__ x_support,
                   const float* __restrict__ table,
                   float* __restrict__ out,
                   unsigned char* __restrict__ bestp,
                   int* __restrict__ wl_cnt,
                   int* __restrict__ wl,
                   int wl_cap,
                   int N)
{
    const int lane = threadIdx.x;
    const int j    = lane & 15;         // A-row index / B-col index
    const int kg   = lane >> 4;         // k-group 0..3 (k = 16h + 4kg + e)
    const int n_off = j >> 2;           // A rows: n_local*4 + m
    const int m     = j & 3;            // m==3 -> zero pad row
    const int by    = blockIdx.y;       // l-half: u = 2*by + uul

    const int n_start = blockIdx.x * 32;   // 8 chunks x 4 n per wave

    // ---- B fragments: 6 tiles (2 u x 3 k), col j <-> support row 48u+3j+k ----
    half4 bh[6][2], bl[6][2];
    #pragma unroll
    for (int uul = 0; uul < 2; ++uul)
        #pragma unroll
        for (int k = 0; k < 3; ++k) {
            const int u = 2 * by + uul;
            const float* bp = x_support + (size_t)(48*u + 3*j + k) * 32 + kg * 4;
            float4 v0 = *(const float4*)bp;
            float4 v1 = *(const float4*)(bp + 16);
            CVT4(bh[3*uul+k][0], bl[3*uul+k][0], v0);
            CVT4(bh[3*uul+k][1], bl[3*uul+k][1], v1);
        }

    // per-lane sup_sq for this lane's l's (l = 16*(2by+uul) + j), hoisted
    float ssq_u[2];
    #pragma unroll
    for (int uul = 0; uul < 2; ++uul)
        ssq_u[uul] = table[(16 * (2*by + uul) + j) * 16 + 10];

    const float4 z4 = make_float4(0.f, 0.f, 0.f, 0.f);

    // prefetch chunk 0's A rows
    float4 pv0, pv1;
    {
        int n_i = n_start + n_off;
        bool ok = (m < 3) && (n_i < N);
        const float* ap = x_neighbor + (size_t)n_i * 96 + m * 32 + kg * 4;
        pv0 = ok ? *(const float4*)ap        : z4;
        pv1 = ok ? *(const float4*)(ap + 16) : z4;
    }

    for (int c8 = 0; c8 < 8; ++c8) {
        const int n_base = n_start + c8 * 4;
        float4 va0 = pv0, va1 = pv1;
        if (c8 < 7) {
            int n_i = n_base + 4 + n_off;
            bool ok = (m < 3) && (n_i < N);
            const float* ap = x_neighbor + (size_t)n_i * 96 + m * 32 + kg * 4;
            pv0 = ok ? *(const float4*)ap        : z4;
            pv1 = ok ? *(const float4*)(ap + 16) : z4;
        }

        // nei_sq: identical reduction order to R9-R11 (bit-identical)
        float rp = va0.x*va0.x + va0.y*va0.y + va0.z*va0.z + va0.w*va0.w
                 + va1.x*va1.x + va1.y*va1.y + va1.z*va1.z + va1.w*va1.w;
        rp += __shfl_xor(rp, 16);
        rp += __shfl_xor(rp, 32);
        float tq = rp + __shfl_xor(rp, 1);
        float nsq4 = tq + __shfl_xor(tq, 2);

        // A fragments (hi/lo, 2 k-halves)
        half4 ah0, al0, ah1, al1;
        CVT4(ah0, al0, va0);
        CVT4(ah1, al1, va1);

        const int n_e  = n_base + kg;
        const float nei_e = __shfl(nsq4, kg * 4);
        const bool nok = (n_e < N);

        #pragma unroll
        for (int uul = 0; uul < 2; ++uul) {
            // 18 MFMAs -> full 3x3 dot matrix of cell (n_e, l)
            f32x4 a0 = {}, a1 = {}, a2 = {};
            MFMA6(a0, 3*uul + 0)
            MFMA6(a1, 3*uul + 1)
            MFMA6(a2, 3*uul + 2)

            // cr[m][k] = a_k[m]; perm sums in the SAME add order as R11
            float c0 = a0[0] + a1[1] + a2[2];   // (0,1,2) -> 6
            float c1 = a0[0] + a2[1] + a1[2];   // (0,2,1) -> 9
            float c2 = a1[0] + a0[1] + a2[2];   // (1,0,2) -> 18
            float c3 = a1[0] + a2[1] + a0[2];   // (1,2,0) -> 24
            float c4 = a2[0] + a0[1] + a1[2];   // (2,0,1) -> 33
            float c5 = a2[0] + a1[1] + a0[2];   // (2,1,0) -> 36

            float b1 = c0, b2 = -3.4e38f; int bpk = 6;
            if (c1 > b1) { b2 = b1; b1 = c1; bpk = 9;  } else if (c1 > b2) b2 = c1;
            if (c2 > b1) { b2 = b1; b1 = c2; bpk = 18; } else if (c2 > b2) b2 = c2;
            if (c3 > b1) { b2 = b1; b1 = c3; bpk = 24; } else if (c3 > b2) b2 = c3;
            if (c4 > b1) { b2 = b1; b1 = c4; bpk = 33; } else if (c4 > b2) b2 = c4;
            if (c5 > b1) { b2 = b1; b1 = c5; bpk = 36; } else if (c5 > b2) b2 = c5;

            if (nok) {
                float dist = nei_e + ssq_u[uul] - 2.0f * b1;
                // atan(1/d) - pi/2 = -atan(d) (d>=0): square removes sign
                float t3 = atanf(dist);
                size_t idx = (size_t)(16 * (2*by + uul) + j) * N + n_e;
                out[idx]   = t3 * t3;
                bestp[idx] = (unsigned char)bpk;
                if (b1 - b2 <= TIE_THR) {
                    int slot = atomicAdd(wl_cnt, 1);
                    if (slot < wl_cap) wl[slot] = (int)idx;
                }
            }
        }
    }
}

// ---------------- Kernel A2: fp64 tie refinement (worklist) ----------------
__global__ __launch_bounds__(256)
void setconvA2(const float* __restrict__ x_neighbor,
               const float* __restrict__ x_support,
               float* __restrict__ out,
               unsigned char* __restrict__ bestp,
               const int* __restrict__ wl_cnt,
               const int* __restrict__ wl,
               int wl_cap,
               int N)
{
    int cnt = *wl_cnt; if (cnt > wl_cap) cnt = wl_cap;
    const int stride = gridDim.x * blockDim.x;
    for (int i = blockIdx.x * blockDim.x + threadIdx.x; i < cnt; i += stride) {
        const int idx = wl[i];
        const int l = idx / N;
        const int n = idx - l * N;
        const float* xn = x_neighbor + (size_t)n * 96;
        const float* xs = x_support  + (size_t)l * 96;

        double dr[3][3] = {{0,0,0},{0,0,0},{0,0,0}};
        double nei = 0.0, ssq = 0.0;
        for (int f = 0; f < 32; ++f) {
            double a0 = (double)xn[f], a1 = (double)xn[32 + f], a2 = (double)xn[64 + f];
            double b0 = (double)xs[f], b1 = (double)xs[32 + f], b2 = (double)xs[64 + f];
            dr[0][0] += a0 * b0; dr[0][1] += a0 * b1; dr[0][2] += a0 * b2;
            dr[1][0] += a1 * b0; dr[1][1] += a1 * b1; dr[1][2] += a1 * b2;
            dr[2][0] += a2 * b0; dr[2][1] += a2 * b1; dr[2][2] += a2 * b2;
            nei += a0 * a0 + a1 * a1 + a2 * a2;
            ssq += b0 * b0 + b1 * b1 + b2 * b2;
        }
        double d0 = dr[0][0] + dr[1][1] + dr[2][2];
        double d1 = dr[0][0] + dr[1][2] + dr[2][1];
        double d2 = dr[0][1] + dr[1][0] + dr[2][2];
        double d3 = dr[0][1] + dr[1][2] + dr[2][0];
        double d4 = dr[0][2] + dr[1][0] + dr[2][1];
        double d5 = dr[0][2] + dr[1][1] + dr[2][0];
        double db = d0; int bpk = 6;
        if (d1 > db) { db = d1; bpk = 9;  }
        if (d2 > db) { db = d2; bpk = 18; }
        if (d3 > db) { db = d3; bpk = 24; }
        if (d4 > db) { db = d4; bpk = 33; }
        if (d5 > db) { db = d5; bpk = 36; }

        float dist = (float)(nei + (double)((float)ssq) - 2.0 * db);
        float t3 = atanf(dist);
        out[idx]   = t3 * t3;
        bestp[idx] = (unsigned char)bpk;
    }
}

// ---------------- Kernel B: value-only scores (fp32, SGPR operands) --------
__global__ __launch_bounds__(128)
void setconvB(const float* __restrict__ x_focal,
              const float* __restrict__ p_focal,
              const float* __restrict__ p_neighbor,
              const float* __restrict__ edge_nei,
              const float* __restrict__ x_center,
              const float* __restrict__ edge_sup,
              const float* __restrict__ table,
              const unsigned char* __restrict__ bestp,
              float* __restrict__ out,
              int N)
{
    const int tid = threadIdx.x;
    const int l0  = blockIdx.y * LCHUNK;
    const int n = blockIdx.x * 128 + tid;
    if (n >= N) return;

    float ed[24], xf[32];
    {
        const float4* q = (const float4*)(edge_nei + (size_t)n * 24);
        #pragma unroll
        for (int i = 0; i < 6; ++i) {
            float4 v = q[i];
            ed[4*i+0] = v.x; ed[4*i+1] = v.y; ed[4*i+2] = v.z; ed[4*i+3] = v.w;
        }
        const float4* r = (const float4*)(x_focal + (size_t)n * 32);
        #pragma unroll
        for (int i = 0; i < 8; ++i) {
            float4 v = r[i];
            xf[4*i+0] = v.x; xf[4*i+1] = v.y; xf[4*i+2] = v.z; xf[4*i+3] = v.w;
        }
    }

    float pr[3][3];
    {
        float pf0 = p_focal[(size_t)n*3 + 0];
        float pf1 = p_focal[(size_t)n*3 + 1];
        float pf2 = p_focal[(size_t)n*3 + 2];
        #pragma unroll
        for (int m = 0; m < 3; ++m) {
            pr[m][0] = p_neighbor[(size_t)n*9 + m*3 + 0] - pf0;
            pr[m][1] = p_neighbor[(size_t)n*9 + m*3 + 1] - pf1;
            pr[m][2] = p_neighbor[(size_t)n*9 + m*3 + 2] - pf2;
        }
    }
    float lenN0 = sqrtf(pr[0][0]*pr[0][0] + pr[0][1]*pr[0][1] + pr[0][2]*pr[0][2]);
    float lenN1 = sqrtf(pr[1][0]*pr[1][0] + pr[1][1]*pr[1][1] + pr[1][2]*pr[1][2]);
    float lenN2 = sqrtf(pr[2][0]*pr[2][0] + pr[2][1]*pr[2][1] + pr[2][2]*pr[2][2]);
    float angN0 = (pr[2][0]*pr[0][0] + pr[2][1]*pr[0][1] + pr[2][2]*pr[0][2]) / fmaxf(lenN2*lenN0, 1e-8f);
    float angN1 = (pr[0][0]*pr[1][0] + pr[0][1]*pr[1][1] + pr[0][2]*pr[1][2]) / fmaxf(lenN0*lenN1, 1e-8f);
    float angN2 = (pr[1][0]*pr[2][0] + pr[1][1]*pr[2][1] + pr[1][2]*pr[2][2]) / fmaxf(lenN1*lenN2, 1e-8f);
    float angN_sq = angN0*angN0 + angN1*angN1 + angN2*angN2;
    float lenN_sq = lenN0*lenN0 + lenN1*lenN1 + lenN2*lenN2;

    float edsq = 0.f, xfsq = 0.f;
    #pragma unroll
    for (int i = 0; i < 24; ++i) edsq = fmaf(ed[i], ed[i], edsq);
    #pragma unroll
    for (int i = 0; i < 32; ++i) xfsq = fmaf(xf[i], xf[i], xfsq);

    for (int ll = 0; ll < LCHUNK; ++ll) {
        const int l = l0 + ll;
        const float* es = edge_sup + (size_t)l * 24;   // uniform -> s_load
        const float* xc = x_center + (size_t)l * 32;   // uniform -> s_load
        const float* tb = table + l * 16;              // uniform -> s_load

        float er[3][3] = {{0,0,0},{0,0,0},{0,0,0}};
        #pragma unroll
        for (int jj = 0; jj < 8; ++jj) {
            float b0 = es[jj], b1 = es[8 + jj], b2 = es[16 + jj];
            float a0 = ed[jj], a1 = ed[8 + jj], a2 = ed[16 + jj];
            er[0][0] = fmaf(a0, b0, er[0][0]);
            er[0][1] = fmaf(a0, b1, er[0][1]);
            er[0][2] = fmaf(a0, b2, er[0][2]);
            er[1][0] = fmaf(a1, b0, er[1][0]);
            er[1][1] = fmaf(a1, b1, er[1][1]);
            er[1][2] = fmaf(a1, b2, er[1][2]);
            er[2][0] = fmaf(a2, b0, er[2][0]);
            er[2][1] = fmaf(a2, b1, er[2][1]);
            er[2][2] = fmaf(a2, b2, er[2][2]);
        }

        float cdot = 0.f;
        #pragma unroll
        for (int f = 0; f < 32; ++f) cdot = fmaf(xf[f], xc[f], cdot);

        size_t idx = (size_t)l * N + n;
        int bp = bestp[idx];
        int a = (bp >> 4) & 3, b = (bp >> 2) & 3, c = bp & 3;

        float e0 = (a == 0) ? er[0][0] : ((a == 1) ? er[0][1] : er[0][2]);
        float e1 = (b == 0) ? er[1][0] : ((b == 1) ? er[1][1] : er[1][2]);
        float e2 = (c == 0) ? er[2][0] : ((c == 1) ? er[2][1] : er[2][2]);
        float bestE = e0 + e1 + e2;

        float n0 = tb[0], n1 = tb[1], n2 = tb[2];
        float C01 = tb[3], C02 = tb[4], C12 = tb[5];
        float la = (a == 0) ? n0 : ((a == 1) ? n1 : n2);
        float lb = (b == 0) ? n0 : ((b == 1) ? n1 : n2);
        float lc = (c == 0) ? n0 : ((c == 1) ? n1 : n2);
        float bestL = fmaf(lenN0, la, fmaf(lenN1, lb, lenN2 * lc));

        int sca = c + a, sab = a + b, sbc = b + c;            // in {1,2,3}
        float Cca = (sca == 1) ? C01 : ((sca == 2) ? C02 : C12);
        float Cab = (sab == 1) ? C01 : ((sab == 2) ? C02 : C12);
        float Cbc = (sbc == 1) ? C01 : ((sbc == 2) ? C02 : C12);
        float bestA = fmaf(angN0, Cca, fmaf(angN1, Cab, angN2 * Cbc));

        // atan(1/d) - pi/2 = -atan(d) for d>=0 -> squares equal, rcp saved
        float t1 = atanf(lenN_sq + tb[7] - 2.0f * bestL);
        float t2 = atanf(angN_sq + tb[6] - 2.0f * bestA);
        float t4 = atanf(xfsq    + tb[9] - 2.0f * cdot);
        float t5 = atanf(edsq    + tb[8] - 2.0f * bestE);

        float h = out[idx] + t1*t1 + t2*t2 + t4*t4 + t5*t5;
        out[idx] = atanf(1.0f / h);
    }
}

extern "C" void kernel_launch(void* const* d_in, const int* in_sizes, int n_in,
                              void* d_out, int out_size, void* d_ws, size_t ws_size,
                              hipStream_t stream)
{
    const float* x_focal    = (const float*)d_in[0];
    const float* p_focal    = (const float*)d_in[1];
    const float* x_neighbor = (const float*)d_in[2];
    const float* p_neighbor = (const float*)d_in[3];
    const float* edge_nei   = (const float*)d_in[4];
    const float* x_center   = (const float*)d_in[5];
    const float* x_support  = (const float*)d_in[6];
    const float* edge_sup   = (const float*)d_in[7];
    const float* p_support  = (const float*)d_in[8];
    float* out = (float*)d_out;

    const int N = in_sizes[0] / 32;                // x_focal is (N, 32)
    const size_t LN = (size_t)L_ * (size_t)N;

    // d_ws layout: [0,4096) table | [4096, 4096+LN) bestp | cnt | worklist
    float* table = (float*)d_ws;
    unsigned char* bestp = (unsigned char*)d_ws + 4096;
    size_t cnt_off = 4096 + ((LN + 15) & ~(size_t)15);
    int* wl_cnt = (int*)((char*)d_ws + cnt_off);
    int* wl     = (int*)((char*)d_ws + cnt_off + 16);
    long cap_l = ((long)ws_size - (long)cnt_off - 16) / 4;
    int wl_cap = cap_l < 0 ? 0 : (cap_l > 2000000 ? 2000000 : (int)cap_l);

    hipMemsetAsync(wl_cnt, 0, sizeof(int), stream);

    setconvP<<<1, 64, 0, stream>>>(x_support, edge_sup, x_center, p_support, table);

    // A: single-wave blocks; grid (n-chunks, 2 l-halves)
    dim3 gridA((N + 31) / 32, 2);
    setconvA_mfma<<<gridA, 64, 0, stream>>>(x_neighbor, x_support, table, out,
                                            bestp, wl_cnt, wl, wl_cap, N);
    setconvA2<<<64, 256, 0, stream>>>(x_neighbor, x_support, out, bestp,
                                      wl_cnt, wl, wl_cap, N);

    dim3 gridB((N + 127) / 128, L_ / LCHUNK);
    setconvB<<<gridB, 128, 0, stream>>>(x_focal, p_focal, p_neighbor, edge_nei,
                                        x_center, edge_sup, table, bestp, out, N);
}